// Round 3
// baseline (1219.231 us; speedup 1.0000x reference)
//
#include <hip/hip_runtime.h>

typedef __attribute__((ext_vector_type(8))) short short8;
typedef __attribute__((ext_vector_type(8))) unsigned short ushortx8;
typedef __attribute__((ext_vector_type(4))) unsigned short ushortx4;
typedef __attribute__((ext_vector_type(4))) float floatx4;

#define SCALE_F 0.08838834764831845f  // 128^-0.5

__device__ __forceinline__ float b2f(unsigned short u) {
  union { unsigned int u; float f; } c; c.u = ((unsigned int)u) << 16; return c.f;
}
__device__ __forceinline__ unsigned short f2b(float f) {
  union { float f; unsigned int u; } c; c.f = f;
  unsigned int u = c.u;
  u += 0x7fffu + ((u >> 16) & 1u);  // RNE; inputs never NaN
  return (unsigned short)(u >> 16);
}

#define GLD_LDS16(g, l)                                              \
  __builtin_amdgcn_global_load_lds(                                  \
      (const __attribute__((address_space(1))) void*)(g),            \
      (__attribute__((address_space(3))) void*)(l), 16, 0, 0)

// ---------------------------------------------------------------------------
// cast fp32 -> bf16 (vectorized x4)
// ---------------------------------------------------------------------------
__global__ __launch_bounds__(256) void cast_bf16_kernel(
    const float* __restrict__ x, unsigned short* __restrict__ y, int n) {
  int i = (blockIdx.x * 256 + threadIdx.x) * 4;
  if (i >= n) return;
  float4 v = *(const float4*)(x + i);
  ushortx4 o;
  o[0] = f2b(v.x); o[1] = f2b(v.y); o[2] = f2b(v.z); o[3] = f2b(v.w);
  *(ushortx4*)(y + i) = o;
}

// ---------------------------------------------------------------------------
// split3: x[R][1024] f32 -> y[R][3072] bf16 = [hi | lo | hi]  (A' operand)
// ---------------------------------------------------------------------------
__global__ __launch_bounds__(256) void split3_kernel(
    const float* __restrict__ x, unsigned short* __restrict__ y) {
  int idx = blockIdx.x * 256 + threadIdx.x;
  int row = idx >> 8;
  int c4 = (idx & 255) * 4;
  float4 v = *(const float4*)(x + (size_t)row * 1024 + c4);
  ushortx4 hi, lo;
  hi[0] = f2b(v.x); lo[0] = f2b(v.x - b2f(hi[0]));
  hi[1] = f2b(v.y); lo[1] = f2b(v.y - b2f(hi[1]));
  hi[2] = f2b(v.z); lo[2] = f2b(v.z - b2f(hi[2]));
  hi[3] = f2b(v.w); lo[3] = f2b(v.w - b2f(hi[3]));
  unsigned short* yr = y + (size_t)row * 3072;
  *(ushortx4*)(yr + c4) = hi;
  *(ushortx4*)(yr + 1024 + c4) = lo;
  *(ushortx4*)(yr + 2048 + c4) = hi;
}

// ---------------------------------------------------------------------------
// transpose+split W_qk[1024][2048] f32 -> y[2048][3072] bf16 = [hi | hi | lo]
// ---------------------------------------------------------------------------
__global__ __launch_bounds__(256) void transpose_split_qk(
    const float* __restrict__ W, unsigned short* __restrict__ y) {
  __shared__ float tile[32][33];
  int t = threadIdx.x, tx = t & 31, ty = t >> 5;
  int n0 = blockIdx.x * 32, k0 = blockIdx.y * 32;
  for (int rr = ty; rr < 32; rr += 8)
    tile[rr][tx] = W[(size_t)(k0 + rr) * 2048 + n0 + tx];
  __syncthreads();
  for (int rr = ty; rr < 32; rr += 8) {
    float v = tile[tx][rr];
    unsigned short hi = f2b(v);
    unsigned short lo = f2b(v - b2f(hi));
    unsigned short* yr = y + (size_t)(n0 + rr) * 3072;
    yr[k0 + tx] = hi;
    yr[1024 + k0 + tx] = hi;
    yr[2048 + k0 + tx] = lo;
  }
}

// ---------------------------------------------------------------------------
// generic 32x32 tiled transpose, batched over (b,h) from p=pstart+z
// MODE 0: f32->bf16   2: bf16->bf16
// ---------------------------------------------------------------------------
template<int MODE>
__global__ __launch_bounds__(256) void transpose_any(
    const void* __restrict__ inv, void* __restrict__ outv,
    int R, int C, int ldin, int ldout,
    long sIb, long sIh, long sOb, long sOh, int pstart) {
  int z = blockIdx.z, p = pstart + z, b = p >> 3, h = p & 7;
  size_t ioff = (size_t)(sIb * b + sIh * h);
  size_t ooff = (size_t)(sOb * b + sOh * h);
  __shared__ float tile[32][33];
  int t = threadIdx.x, tx = t & 31, ty = t >> 5;
  int c0 = blockIdx.x * 32, r0 = blockIdx.y * 32;
  for (int rr = ty; rr < 32; rr += 8) {
    size_t idx = ioff + (size_t)(r0 + rr) * ldin + (c0 + tx);
    tile[rr][tx] = (MODE == 2) ? b2f(((const unsigned short*)inv)[idx])
                               : ((const float*)inv)[idx];
  }
  __syncthreads();
  for (int rr = ty; rr < 32; rr += 8) {
    size_t idx = ooff + (size_t)(c0 + rr) * ldout + (r0 + tx);
    ((unsigned short*)outv)[idx] = f2b(tile[tx][rr]);
  }
}

// ---------------------------------------------------------------------------
// m97-style bf16 MFMA GEMM: C[M][N] = A[M][K] @ BT[N][K]^T
// 128x128 tile, BK=32, 256 thr = 4 waves, wave = 64x64 quadrant = 4x4 MFMA
// ---------------------------------------------------------------------------
template<int OUT_BF16, int ADD_BIAS>
__global__ __launch_bounds__(256) void gemm128(
    const unsigned short* __restrict__ A, const unsigned short* __restrict__ BT,
    void* __restrict__ Cv, const float* __restrict__ bias,
    int K, int lda, int ldb, int ldc,
    long sAz, long sAb, long sAh, long sBz, long sBb, long sBh,
    long sCz, long sCb, long sCh, int pstart) {
  int z = blockIdx.z, p = pstart + z, bb = p >> 3, hh = p & 7;
  A  += (size_t)(sAz * z + sAb * bb + sAh * hh);
  BT += (size_t)(sBz * z + sBb * bb + sBh * hh);
  size_t coff = (size_t)(sCz * z + sCb * bb + sCh * hh);

  __shared__ unsigned short Al[128][32];
  __shared__ unsigned short Bl[128][32];
  int t = threadIdx.x;
  int m0 = blockIdx.y * 128, n0 = blockIdx.x * 128;
  int w = t >> 6, l = t & 63;
  int wm = (w >> 1) * 64, wn = (w & 1) * 64;
  int lrow = l & 15, lq = l >> 4;
  floatx4 acc[4][4] = {};

  int srow = t >> 2, scol = (t & 3) * 8;
  const unsigned short* ga = A + (size_t)(m0 + srow) * lda + scol;
  const unsigned short* gb = BT + (size_t)(n0 + srow) * ldb + scol;
  unsigned short* la = &Al[srow][scol];
  unsigned short* lb = &Bl[srow][scol];
  size_t lda64 = (size_t)64 * lda, ldb64 = (size_t)64 * ldb;

  for (int k0 = 0; k0 < K; k0 += 32) {
    GLD_LDS16(ga + k0, la);
    GLD_LDS16(ga + lda64 + k0, la + 64 * 32);
    GLD_LDS16(gb + k0, lb);
    GLD_LDS16(gb + ldb64 + k0, lb + 64 * 32);
    __syncthreads();
    short8 af[4], bf[4];
#pragma unroll
    for (int i = 0; i < 4; i++) af[i] = *(const short8*)&Al[wm + i * 16 + lrow][lq * 8];
#pragma unroll
    for (int j = 0; j < 4; j++) bf[j] = *(const short8*)&Bl[wn + j * 16 + lrow][lq * 8];
#pragma unroll
    for (int i = 0; i < 4; i++)
#pragma unroll
      for (int j = 0; j < 4; j++)
        acc[i][j] = __builtin_amdgcn_mfma_f32_16x16x32_bf16(af[i], bf[j], acc[i][j], 0, 0, 0);
    __syncthreads();
  }
#pragma unroll
  for (int i = 0; i < 4; i++)
#pragma unroll
    for (int j = 0; j < 4; j++)
#pragma unroll
      for (int r = 0; r < 4; r++) {
        int row = m0 + wm + i * 16 + lq * 4 + r;
        int col = n0 + wn + j * 16 + lrow;
        float v = acc[i][j][r];
        if (ADD_BIAS) v += bias[col];
        size_t idx = coff + (size_t)row * ldc + col;
        if (OUT_BF16) ((unsigned short*)Cv)[idx] = f2b(v);
        else          ((float*)Cv)[idx] = v;
      }
}

// ---------------------------------------------------------------------------
// logits prep (per 16-pair chunk): qkf fp32 -> qm[z][1024][384]=[hi|lo|hi],
//                                           km[z][1024][384]=[hi|hi|lo]
// ---------------------------------------------------------------------------
__global__ __launch_bounds__(256) void logits_prep(
    const float* __restrict__ qkf, unsigned short* __restrict__ qm,
    unsigned short* __restrict__ km, int pstart) {
  int idx = blockIdx.x * 256 + threadIdx.x;
  int z = blockIdx.y;
  int i = idx >> 5;
  int d4 = (idx & 31) * 4;
  int p = pstart + z, b = p >> 3, h = p & 7;
  const float* row = qkf + ((size_t)(b * 1024 + i)) * 2048 + h * 128;
  ushortx4 hi, lo;

  float4 q = *(const float4*)(row + d4);
  hi[0] = f2b(q.x); lo[0] = f2b(q.x - b2f(hi[0]));
  hi[1] = f2b(q.y); lo[1] = f2b(q.y - b2f(hi[1]));
  hi[2] = f2b(q.z); lo[2] = f2b(q.z - b2f(hi[2]));
  hi[3] = f2b(q.w); lo[3] = f2b(q.w - b2f(hi[3]));
  unsigned short* qr = qm + ((size_t)z * 1024 + i) * 384;
  *(ushortx4*)(qr + d4) = hi;
  *(ushortx4*)(qr + 128 + d4) = lo;
  *(ushortx4*)(qr + 256 + d4) = hi;

  float4 k = *(const float4*)(row + 1024 + d4);
  hi[0] = f2b(k.x); lo[0] = f2b(k.x - b2f(hi[0]));
  hi[1] = f2b(k.y); lo[1] = f2b(k.y - b2f(hi[1]));
  hi[2] = f2b(k.z); lo[2] = f2b(k.z - b2f(hi[2]));
  hi[3] = f2b(k.w); lo[3] = f2b(k.w - b2f(hi[3]));
  unsigned short* kr = km + ((size_t)z * 1024 + i) * 384;
  *(ushortx4*)(kr + d4) = hi;
  *(ushortx4*)(kr + 128 + d4) = hi;
  *(ushortx4*)(kr + 256 + d4) = lo;
}

// ---------------------------------------------------------------------------
// row stats of the inner softmax: M_i = rowmax(smb), L_i = rowsum(exp(x-M))
// one block per row; mlb[z][0][row]=M, mlb[z][1][row]=L
// ---------------------------------------------------------------------------
__global__ __launch_bounds__(256) void row_stats(
    const float* __restrict__ smb, float* __restrict__ mlb) {
  int row = blockIdx.x, z = blockIdx.y, t = threadIdx.x;
  const float* sr = smb + ((size_t)z * 1024 + row) * 1024;
  __shared__ float red[4];
  float4 v = *(const float4*)(sr + t * 4);
  float mx = fmaxf(fmaxf(v.x, v.y), fmaxf(v.z, v.w));
#pragma unroll
  for (int o = 32; o; o >>= 1) mx = fmaxf(mx, __shfl_xor(mx, o));
  if ((t & 63) == 0) red[t >> 6] = mx;
  __syncthreads();
  mx = fmaxf(fmaxf(red[0], red[1]), fmaxf(red[2], red[3]));
  __syncthreads();
  float s = __expf(v.x - mx) + __expf(v.y - mx) + __expf(v.z - mx) + __expf(v.w - mx);
#pragma unroll
  for (int o = 32; o; o >>= 1) s += __shfl_xor(s, o);
  if ((t & 63) == 0) red[t >> 6] = s;
  __syncthreads();
  if (t == 0) {
    mlb[z * 2048 + row] = mx;
    mlb[z * 2048 + 1024 + row] = red[0] + red[1] + red[2] + red[3];
  }
}

// ---------------------------------------------------------------------------
// fused attention middle: per block = 32 Q-rows of one (b,h) pair.
// loop j-tiles of 128 keys:
//   p_v tile = q_v @ k_v^T (MFMA, q_v frags register-resident)
//   dots = exp(sm - M)/L * p_v * SCALE + g_l     (sm, g_l read scattered)
//   online outer softmax (cross-wave max via LDS), attn -> bf16
//   LDS transpose C-layout -> A-layout (pad +8 shorts: 2-way banks, free)
//   O += attn @ v (MFMA, v^T staged via global_load_lds)
// epilogue: O / l2 -> ao (scattered bf16, [b*1024+i][h*128+d])
// wave w covers cols [w*32, w*32+32) of the 128-wide tile (pv: key-cols; PV: d)
// lane holds rows i*16+lq*4+r (i<2, r<4) -> 8 row-stat slots per lane
// ---------------------------------------------------------------------------
__global__ __launch_bounds__(256) void attn_pv(
    const unsigned short* __restrict__ qkv, const unsigned short* __restrict__ vt,
    const float* __restrict__ smb, const float* __restrict__ mlb,
    const float* __restrict__ g_l, unsigned short* __restrict__ ao, int pstart) {
  int z = blockIdx.y, p = pstart + z, b = p >> 3, h = p & 7;
  int r0 = blockIdx.x * 32;
  int t = threadIdx.x, w = t >> 6, l = t & 63;
  int lrow = l & 15, lq = l >> 4;
  int wc = w * 32;
  int sr = t >> 2, sc = (t & 3) * 8;

  __shared__ unsigned short kvl[128][32];
  __shared__ unsigned short vtl[128][32];
  __shared__ unsigned short attnl[32][136];
  __shared__ float mex[4][32];
  __shared__ float lex[4][32];

  // resident q_v A-fragments (4 K-chunks x 2 row-frags)
  short8 aq[4][2];
#pragma unroll
  for (int kc = 0; kc < 4; kc++)
#pragma unroll
    for (int i = 0; i < 2; i++)
      aq[kc][i] = *(const short8*)(qkv +
          (size_t)(b * 1024 + r0 + i * 16 + lrow) * 3072 + h * 128 + kc * 32 + lq * 8);

  // inner-softmax row stats
  float Mr[8], Li[8];
#pragma unroll
  for (int i = 0; i < 2; i++)
#pragma unroll
    for (int r = 0; r < 4; r++) {
      int rw = i * 16 + lq * 4 + r;
      Mr[i * 4 + r] = mlb[z * 2048 + r0 + rw];
      Li[i * 4 + r] = 1.0f / mlb[z * 2048 + 1024 + r0 + rw];
    }

  float m2[8], l2[8];
#pragma unroll
  for (int ri = 0; ri < 8; ri++) { m2[ri] = -1e30f; l2[ri] = 0.f; }
  floatx4 Og[2][2] = {};

  const size_t smrow0 = (size_t)z * 1024 + r0;
  const size_t glrow0 = (size_t)p * 1024 + r0;
  const size_t vbase = (size_t)p * 131072;
  const size_t kvbase = (size_t)b * 1024 * 3072 + 1024 + h * 128;

  for (int j0 = 0; j0 < 1024; j0 += 128) {
    // ---- p_v tile
    floatx4 pva[2][2] = {};
#pragma unroll
    for (int kc = 0; kc < 4; kc++) {
      __syncthreads();
      GLD_LDS16(qkv + kvbase + (size_t)(j0 + sr) * 3072 + kc * 32 + sc, &kvl[sr][sc]);
      GLD_LDS16(qkv + kvbase + (size_t)(j0 + 64 + sr) * 3072 + kc * 32 + sc, &kvl[sr + 64][sc]);
      __syncthreads();
#pragma unroll
      for (int i = 0; i < 2; i++)
#pragma unroll
        for (int jj = 0; jj < 2; jj++) {
          short8 bf = *(const short8*)&kvl[wc + jj * 16 + lrow][lq * 8];
          pva[i][jj] = __builtin_amdgcn_mfma_f32_16x16x32_bf16(aq[kc][i], bf, pva[i][jj], 0, 0, 0);
        }
    }
    // ---- combine with inner softmax + g_l
    float dv[2][2][4];
#pragma unroll
    for (int i = 0; i < 2; i++)
#pragma unroll
      for (int r = 0; r < 4; r++) {
        size_t ro = (smrow0 + i * 16 + lq * 4 + r) * 1024;
        size_t go = (glrow0 + i * 16 + lq * 4 + r) * 1024;
        float M = Mr[i * 4 + r], Lv = Li[i * 4 + r];
#pragma unroll
        for (int jj = 0; jj < 2; jj++) {
          int col = j0 + wc + jj * 16 + lrow;
          float sm = smb[ro + col];
          float g = g_l[go + col];
          float pm = __expf(sm - M) * Lv;
          dv[i][jj][r] = pm * pva[i][jj][r] * SCALE_F + g;
        }
      }
    // ---- outer online softmax: cross-lane + cross-wave row max
    float lmax[8];
#pragma unroll
    for (int i = 0; i < 2; i++)
#pragma unroll
      for (int r = 0; r < 4; r++) {
        float m = fmaxf(dv[i][0][r], dv[i][1][r]);
#pragma unroll
        for (int o = 1; o < 16; o <<= 1) m = fmaxf(m, __shfl_xor(m, o));
        lmax[i * 4 + r] = m;
      }
    if (lrow == 0) {
#pragma unroll
      for (int i = 0; i < 2; i++)
#pragma unroll
        for (int r = 0; r < 4; r++)
          mex[w][i * 16 + lq * 4 + r] = lmax[i * 4 + r];
    }
    __syncthreads();
    float alpha[8];
#pragma unroll
    for (int i = 0; i < 2; i++)
#pragma unroll
      for (int r = 0; r < 4; r++) {
        int ri = i * 4 + r, rw = i * 16 + lq * 4 + r;
        float mn = fmaxf(fmaxf(mex[0][rw], mex[1][rw]), fmaxf(mex[2][rw], mex[3][rw]));
        mn = fmaxf(mn, m2[ri]);
        alpha[ri] = __expf(m2[ri] - mn);
        m2[ri] = mn;
      }
    float ev[2][2][4];
#pragma unroll
    for (int i = 0; i < 2; i++)
#pragma unroll
      for (int r = 0; r < 4; r++) {
        int ri = i * 4 + r;
        float e0 = __expf(dv[i][0][r] - m2[ri]);
        float e1 = __expf(dv[i][1][r] - m2[ri]);
        ev[i][0][r] = e0; ev[i][1][r] = e1;
        float rs = e0 + e1;
#pragma unroll
        for (int o = 1; o < 16; o <<= 1) rs += __shfl_xor(rs, o);
        l2[ri] = l2[ri] * alpha[ri] + rs;
#pragma unroll
        for (int jj = 0; jj < 2; jj++) Og[i][jj][r] *= alpha[ri];
      }
    // ---- attn -> LDS (A-layout source), then O += attn @ v
#pragma unroll
    for (int i = 0; i < 2; i++)
#pragma unroll
      for (int jj = 0; jj < 2; jj++)
#pragma unroll
        for (int r = 0; r < 4; r++)
          attnl[i * 16 + lq * 4 + r][wc + jj * 16 + lrow] = f2b(ev[i][jj][r]);
    __syncthreads();
#pragma unroll
    for (int kc = 0; kc < 4; kc++) {
      GLD_LDS16(vt + vbase + (size_t)sr * 1024 + j0 + kc * 32 + sc, &vtl[sr][sc]);
      GLD_LDS16(vt + vbase + (size_t)(sr + 64) * 1024 + j0 + kc * 32 + sc, &vtl[sr + 64][sc]);
      __syncthreads();
#pragma unroll
      for (int i = 0; i < 2; i++) {
        short8 af = *(const short8*)&attnl[i * 16 + lrow][kc * 32 + lq * 8];
#pragma unroll
        for (int jj = 0; jj < 2; jj++) {
          short8 bf = *(const short8*)&vtl[wc + jj * 16 + lrow][lq * 8];
          Og[i][jj] = __builtin_amdgcn_mfma_f32_16x16x32_bf16(af, bf, Og[i][jj], 0, 0, 0);
        }
      }
      if (kc < 3) __syncthreads();
    }
  }
  // ---- epilogue: combine l2 across the 4 column-waves, write ao
  if (lrow == 0) {
#pragma unroll
    for (int i = 0; i < 2; i++)
#pragma unroll
      for (int r = 0; r < 4; r++)
        lex[w][i * 16 + lq * 4 + r] = l2[i * 4 + r];
  }
  __syncthreads();
#pragma unroll
  for (int i = 0; i < 2; i++)
#pragma unroll
    for (int r = 0; r < 4; r++) {
      int rw = i * 16 + lq * 4 + r;
      float inv = 1.0f / (lex[0][rw] + lex[1][rw] + lex[2][rw] + lex[3][rw]);
#pragma unroll
      for (int jj = 0; jj < 2; jj++)
        ao[(size_t)(b * 1024 + r0 + rw) * 1024 + h * 128 + wc + jj * 16 + lrow] =
            f2b(Og[i][jj][r] * inv);
    }
}

// ---------------------------------------------------------------------------
// launch
// ---------------------------------------------------------------------------
extern "C" void kernel_launch(void* const* d_in, const int* in_sizes, int n_in,
                              void* d_out, int out_size, void* d_ws, size_t ws_size,
                              hipStream_t stream) {
  (void)in_sizes; (void)n_in; (void)out_size; (void)ws_size;
  const float* s_v   = (const float*)d_in[0];
  const float* s_m   = (const float*)d_in[1];
  const float* g_l   = (const float*)d_in[2];
  const float* W_qkv = (const float*)d_in[3];
  const float* W_qk  = (const float*)d_in[4];
  const float* W_out = (const float*)d_in[5];
  const float* b_out = (const float*)d_in[6];
  float* out = (float*)d_out;
  char* ws = (char*)d_ws;

  // workspace (<= 283 MB; phase-aliased regions marked A:/B:)
  unsigned short* sv_bf  = (unsigned short*)(ws);              // A: s_v bf16 16M
  unsigned short* qm384  = (unsigned short*)(ws);              // B: alias, 12.6M
  unsigned short* wtqkv  = (unsigned short*)(ws + 16777216);   // A: 6.3M
  unsigned short* km384  = (unsigned short*)(ws + 16777216);   // B: alias, 12.6M
  unsigned short* wtout  = (unsigned short*)(ws + 29360128);   // persistent 2M
  unsigned short* qkvb   = (unsigned short*)(ws + 31457280);   // persistent 48M
  float*          qkf    = (float*)(ws + 81788928);            // persistent 64M
  unsigned short* vt     = (unsigned short*)(ws + 148897792);  // persistent 16M
  unsigned short* ao     = (unsigned short*)(ws + 165675008);  // persistent 16M
  unsigned short* smhl   = (unsigned short*)(ws + 182452224);  // A: 48M
  float*          smb    = (float*)(ws + 182452224);           // B: alias, 64M
  unsigned short* wqk_hl = (unsigned short*)(ws + 249561088);  // A: 12.6M
  float*          mlb    = (float*)(ws + 249561088);           // B: alias, 131K

  // 1. cast s_v -> bf16
  cast_bf16_kernel<<<dim3(8192), 256, 0, stream>>>(s_v, sv_bf, 8388608);
  // 2-3. weight transposes (bf16)
  transpose_any<0><<<dim3(96, 32, 1), 256, 0, stream>>>(
      W_qkv, wtqkv, 1024, 3072, 3072, 1024, 0, 0, 0, 0, 0);
  transpose_any<0><<<dim3(32, 32, 1), 256, 0, stream>>>(
      W_out, wtout, 1024, 1024, 1024, 1024, 0, 0, 0, 0, 0);
  // 4. split s_m -> [hi|lo|hi]
  split3_kernel<<<dim3(8192), 256, 0, stream>>>(s_m, smhl);
  // 5. transpose+split W_qk -> [2048][3072] = [hi|hi|lo]
  transpose_split_qk<<<dim3(64, 32, 1), 256, 0, stream>>>(W_qk, wqk_hl);
  // 6. qkv = s_v @ W_qkv  (bf16 MFMA 128-tile)
  gemm128<1, 0><<<dim3(24, 64, 1), 256, 0, stream>>>(
      sv_bf, wtqkv, qkvb, nullptr, 1024, 1024, 1024, 3072,
      0, 0, 0, 0, 0, 0, 0, 0, 0, 0);
  // 7. qk = s_m @ W_qk in split-bf16 (K=3072), fp32 out
  gemm128<0, 0><<<dim3(16, 64, 1), 256, 0, stream>>>(
      smhl, wqk_hl, qkf, nullptr, 3072, 3072, 3072, 2048,
      0, 0, 0, 0, 0, 0, 0, 0, 0, 0);
  // 8. v^T per (b,h): vt[p][d][j]
  transpose_any<2><<<dim3(4, 32, 64), 256, 0, stream>>>(
      qkvb + 2048, vt, 1024, 128, 3072, 1024,
      (long)1024 * 3072, 128, (long)1048576, 131072, 0);

  // 9. chunks of 16 (b,h)-pairs
  for (int c = 0; c < 4; c++) {
    int pstart = c * 16;
    logits_prep<<<dim3(128, 16), 256, 0, stream>>>(qkf, qm384, km384, pstart);
    // s_m logits via split-bf16 (K=384), fp32 out
    gemm128<0, 0><<<dim3(8, 8, 16), 256, 0, stream>>>(
        qm384, km384, smb, nullptr, 384, 384, 384, 1024,
        (long)1024 * 384, 0, 0, (long)1024 * 384, 0, 0,
        (long)1048576, 0, 0, pstart);
    // inner softmax row stats
    row_stats<<<dim3(1024, 16), 256, 0, stream>>>(smb, mlb);
    // fused p_v + combine + outer softmax + attn@v
    attn_pv<<<dim3(32, 16), 256, 0, stream>>>(
        qkvb, vt, smb, mlb, g_l, ao, pstart);
  }
  // 10. out = ao @ W_out + b_out (fp32 out)
  gemm128<0, 1><<<dim3(8, 64, 1), 256, 0, stream>>>(
      ao, wtout, out, b_out, 1024, 1024, 1024, 1024,
      0, 0, 0, 0, 0, 0, 0, 0, 0, 0);
}

// Round 4
// 1059.234 us; speedup vs baseline: 1.1511x; 1.1511x over previous
//
#include <hip/hip_runtime.h>

typedef __attribute__((ext_vector_type(8))) short short8;
typedef __attribute__((ext_vector_type(8))) unsigned short ushortx8;
typedef __attribute__((ext_vector_type(4))) unsigned short ushortx4;
typedef __attribute__((ext_vector_type(4))) float floatx4;

#define SCALE_F 0.08838834764831845f  // 128^-0.5

__device__ __forceinline__ float b2f(unsigned short u) {
  union { unsigned int u; float f; } c; c.u = ((unsigned int)u) << 16; return c.f;
}
__device__ __forceinline__ unsigned short f2b(float f) {
  union { float f; unsigned int u; } c; c.f = f;
  unsigned int u = c.u;
  u += 0x7fffu + ((u >> 16) & 1u);  // RNE; inputs never NaN
  return (unsigned short)(u >> 16);
}

#define GLD_LDS16(g, l)                                              \
  __builtin_amdgcn_global_load_lds(                                  \
      (const __attribute__((address_space(1))) void*)(g),            \
      (__attribute__((address_space(3))) void*)(l), 16, 0, 0)

// ---------------------------------------------------------------------------
// cast fp32 -> bf16 (vectorized x4)
// ---------------------------------------------------------------------------
__global__ __launch_bounds__(256) void cast_bf16_kernel(
    const float* __restrict__ x, unsigned short* __restrict__ y, int n) {
  int i = (blockIdx.x * 256 + threadIdx.x) * 4;
  if (i >= n) return;
  float4 v = *(const float4*)(x + i);
  ushortx4 o;
  o[0] = f2b(v.x); o[1] = f2b(v.y); o[2] = f2b(v.z); o[3] = f2b(v.w);
  *(ushortx4*)(y + i) = o;
}

// ---------------------------------------------------------------------------
// split2: x[R][1024] f32 -> y[R][2048] bf16 = [hi | lo]  (projection A')
// ---------------------------------------------------------------------------
__global__ __launch_bounds__(256) void split2_kernel(
    const float* __restrict__ x, unsigned short* __restrict__ y) {
  int idx = blockIdx.x * 256 + threadIdx.x;
  int row = idx >> 8;
  int c4 = (idx & 255) * 4;
  float4 v = *(const float4*)(x + (size_t)row * 1024 + c4);
  ushortx4 hi, lo;
  hi[0] = f2b(v.x); lo[0] = f2b(v.x - b2f(hi[0]));
  hi[1] = f2b(v.y); lo[1] = f2b(v.y - b2f(hi[1]));
  hi[2] = f2b(v.z); lo[2] = f2b(v.z - b2f(hi[2]));
  hi[3] = f2b(v.w); lo[3] = f2b(v.w - b2f(hi[3]));
  unsigned short* yr = y + (size_t)row * 2048;
  *(ushortx4*)(yr + c4) = hi;
  *(ushortx4*)(yr + 1024 + c4) = lo;
}

// ---------------------------------------------------------------------------
// transpose+split W_qk[1024][2048] f32 -> y[2048][2048] bf16 = [hi | hi]
// pairs with A'=[hi|lo]: sum = hi_a*hi_b + lo_a*hi_b  (hi_a*lo_b omitted)
// ---------------------------------------------------------------------------
__global__ __launch_bounds__(256) void transpose_split_qk(
    const float* __restrict__ W, unsigned short* __restrict__ y) {
  __shared__ float tile[32][33];
  int t = threadIdx.x, tx = t & 31, ty = t >> 5;
  int n0 = blockIdx.x * 32, k0 = blockIdx.y * 32;
  for (int rr = ty; rr < 32; rr += 8)
    tile[rr][tx] = W[(size_t)(k0 + rr) * 2048 + n0 + tx];
  __syncthreads();
  for (int rr = ty; rr < 32; rr += 8) {
    float v = tile[tx][rr];
    unsigned short hi = f2b(v);
    unsigned short* yr = y + (size_t)(n0 + rr) * 2048;
    yr[k0 + tx] = hi;
    yr[1024 + k0 + tx] = hi;
  }
}

// ---------------------------------------------------------------------------
// generic 32x32 tiled transpose, batched over (b,h) from p=pstart+z
// MODE 0: f32->bf16   2: bf16->bf16
// ---------------------------------------------------------------------------
template<int MODE>
__global__ __launch_bounds__(256) void transpose_any(
    const void* __restrict__ inv, void* __restrict__ outv,
    int R, int C, int ldin, int ldout,
    long sIb, long sIh, long sOb, long sOh, int pstart) {
  int z = blockIdx.z, p = pstart + z, b = p >> 3, h = p & 7;
  size_t ioff = (size_t)(sIb * b + sIh * h);
  size_t ooff = (size_t)(sOb * b + sOh * h);
  __shared__ float tile[32][33];
  int t = threadIdx.x, tx = t & 31, ty = t >> 5;
  int c0 = blockIdx.x * 32, r0 = blockIdx.y * 32;
  for (int rr = ty; rr < 32; rr += 8) {
    size_t idx = ioff + (size_t)(r0 + rr) * ldin + (c0 + tx);
    tile[rr][tx] = (MODE == 2) ? b2f(((const unsigned short*)inv)[idx])
                               : ((const float*)inv)[idx];
  }
  __syncthreads();
  for (int rr = ty; rr < 32; rr += 8) {
    size_t idx = ooff + (size_t)(c0 + rr) * ldout + (r0 + tx);
    ((unsigned short*)outv)[idx] = f2b(tile[tx][rr]);
  }
}

// ---------------------------------------------------------------------------
// m97-style bf16 MFMA GEMM: C[M][N] = A[M][K] @ BT[N][K]^T
// 128x128 tile, BK=32, 256 thr = 4 waves, wave = 64x64 quadrant = 4x4 MFMA
// ---------------------------------------------------------------------------
template<int OUT_BF16, int ADD_BIAS>
__global__ __launch_bounds__(256) void gemm128(
    const unsigned short* __restrict__ A, const unsigned short* __restrict__ BT,
    void* __restrict__ Cv, const float* __restrict__ bias,
    int K, int lda, int ldb, int ldc,
    long sAz, long sAb, long sAh, long sBz, long sBb, long sBh,
    long sCz, long sCb, long sCh, int pstart) {
  int z = blockIdx.z, p = pstart + z, bb = p >> 3, hh = p & 7;
  A  += (size_t)(sAz * z + sAb * bb + sAh * hh);
  BT += (size_t)(sBz * z + sBb * bb + sBh * hh);
  size_t coff = (size_t)(sCz * z + sCb * bb + sCh * hh);

  __shared__ unsigned short Al[128][32];
  __shared__ unsigned short Bl[128][32];
  int t = threadIdx.x;
  int m0 = blockIdx.y * 128, n0 = blockIdx.x * 128;
  int w = t >> 6, l = t & 63;
  int wm = (w >> 1) * 64, wn = (w & 1) * 64;
  int lrow = l & 15, lq = l >> 4;
  floatx4 acc[4][4] = {};

  int srow = t >> 2, scol = (t & 3) * 8;
  const unsigned short* ga = A + (size_t)(m0 + srow) * lda + scol;
  const unsigned short* gb = BT + (size_t)(n0 + srow) * ldb + scol;
  unsigned short* la = &Al[srow][scol];
  unsigned short* lb = &Bl[srow][scol];
  size_t lda64 = (size_t)64 * lda, ldb64 = (size_t)64 * ldb;

  for (int k0 = 0; k0 < K; k0 += 32) {
    GLD_LDS16(ga + k0, la);
    GLD_LDS16(ga + lda64 + k0, la + 64 * 32);
    GLD_LDS16(gb + k0, lb);
    GLD_LDS16(gb + ldb64 + k0, lb + 64 * 32);
    __syncthreads();
    short8 af[4], bf[4];
#pragma unroll
    for (int i = 0; i < 4; i++) af[i] = *(const short8*)&Al[wm + i * 16 + lrow][lq * 8];
#pragma unroll
    for (int j = 0; j < 4; j++) bf[j] = *(const short8*)&Bl[wn + j * 16 + lrow][lq * 8];
#pragma unroll
    for (int i = 0; i < 4; i++)
#pragma unroll
      for (int j = 0; j < 4; j++)
        acc[i][j] = __builtin_amdgcn_mfma_f32_16x16x32_bf16(af[i], bf[j], acc[i][j], 0, 0, 0);
    __syncthreads();
  }
#pragma unroll
  for (int i = 0; i < 4; i++)
#pragma unroll
    for (int j = 0; j < 4; j++)
#pragma unroll
      for (int r = 0; r < 4; r++) {
        int row = m0 + wm + i * 16 + lq * 4 + r;
        int col = n0 + wn + j * 16 + lrow;
        float v = acc[i][j][r];
        if (ADD_BIAS) v += bias[col];
        size_t idx = coff + (size_t)row * ldc + col;
        if (OUT_BF16) ((unsigned short*)Cv)[idx] = f2b(v);
        else          ((float*)Cv)[idx] = v;
      }
}

// ---------------------------------------------------------------------------
// gemm64: 64(M)x128(N) tile variant (for skinny-M GEMMs like attn@v) — gives
// 2x the blocks of gemm128 when M is small. 4 waves: wave = 32x64, 2x4 MFMA.
// ---------------------------------------------------------------------------
template<int OUT_BF16, int ADD_BIAS>
__global__ __launch_bounds__(256) void gemm64(
    const unsigned short* __restrict__ A, const unsigned short* __restrict__ BT,
    void* __restrict__ Cv, const float* __restrict__ bias,
    int K, int lda, int ldb, int ldc,
    long sAz, long sAb, long sAh, long sBz, long sBb, long sBh,
    long sCz, long sCb, long sCh, int pstart) {
  int z = blockIdx.z, p = pstart + z, bb = p >> 3, hh = p & 7;
  A  += (size_t)(sAz * z + sAb * bb + sAh * hh);
  BT += (size_t)(sBz * z + sBb * bb + sBh * hh);
  size_t coff = (size_t)(sCz * z + sCb * bb + sCh * hh);

  __shared__ unsigned short Al[64][32];
  __shared__ unsigned short Bl[128][32];
  int t = threadIdx.x;
  int m0 = blockIdx.y * 64, n0 = blockIdx.x * 128;
  int w = t >> 6, l = t & 63;
  int wm = (w >> 1) * 32, wn = (w & 1) * 64;
  int lrow = l & 15, lq = l >> 4;
  floatx4 acc[2][4] = {};

  int srow = t >> 2, scol = (t & 3) * 8;
  const unsigned short* ga = A + (size_t)(m0 + srow) * lda + scol;
  const unsigned short* gb = BT + (size_t)(n0 + srow) * ldb + scol;
  unsigned short* la = &Al[srow][scol];
  unsigned short* lb = &Bl[srow][scol];
  size_t ldb64 = (size_t)64 * ldb;

  for (int k0 = 0; k0 < K; k0 += 32) {
    GLD_LDS16(ga + k0, la);
    GLD_LDS16(gb + k0, lb);
    GLD_LDS16(gb + ldb64 + k0, lb + 64 * 32);
    __syncthreads();
    short8 af[2], bf[4];
#pragma unroll
    for (int i = 0; i < 2; i++) af[i] = *(const short8*)&Al[wm + i * 16 + lrow][lq * 8];
#pragma unroll
    for (int j = 0; j < 4; j++) bf[j] = *(const short8*)&Bl[wn + j * 16 + lrow][lq * 8];
#pragma unroll
    for (int i = 0; i < 2; i++)
#pragma unroll
      for (int j = 0; j < 4; j++)
        acc[i][j] = __builtin_amdgcn_mfma_f32_16x16x32_bf16(af[i], bf[j], acc[i][j], 0, 0, 0);
    __syncthreads();
  }
#pragma unroll
  for (int i = 0; i < 2; i++)
#pragma unroll
    for (int j = 0; j < 4; j++)
#pragma unroll
      for (int r = 0; r < 4; r++) {
        int row = m0 + wm + i * 16 + lq * 4 + r;
        int col = n0 + wn + j * 16 + lrow;
        float v = acc[i][j][r];
        if (ADD_BIAS) v += bias[col];
        size_t idx = coff + (size_t)row * ldc + col;
        if (OUT_BF16) ((unsigned short*)Cv)[idx] = f2b(v);
        else          ((float*)Cv)[idx] = v;
      }
}

// ---------------------------------------------------------------------------
// logits prep (per 16-pair chunk): qkf fp32 -> qm[z][1024][384]=[hi|lo|hi],
//                                           km[z][1024][384]=[hi|hi|lo]
// (3-term split kept here: logits are the precision-critical dot products)
// ---------------------------------------------------------------------------
__global__ __launch_bounds__(256) void logits_prep(
    const float* __restrict__ qkf, unsigned short* __restrict__ qm,
    unsigned short* __restrict__ km, int pstart) {
  int idx = blockIdx.x * 256 + threadIdx.x;
  int z = blockIdx.y;
  int i = idx >> 5;
  int d4 = (idx & 31) * 4;
  int p = pstart + z, b = p >> 3, h = p & 7;
  const float* row = qkf + ((size_t)(b * 1024 + i)) * 2048 + h * 128;
  ushortx4 hi, lo;

  float4 q = *(const float4*)(row + d4);
  hi[0] = f2b(q.x); lo[0] = f2b(q.x - b2f(hi[0]));
  hi[1] = f2b(q.y); lo[1] = f2b(q.y - b2f(hi[1]));
  hi[2] = f2b(q.z); lo[2] = f2b(q.z - b2f(hi[2]));
  hi[3] = f2b(q.w); lo[3] = f2b(q.w - b2f(hi[3]));
  unsigned short* qr = qm + ((size_t)z * 1024 + i) * 384;
  *(ushortx4*)(qr + d4) = hi;
  *(ushortx4*)(qr + 128 + d4) = lo;
  *(ushortx4*)(qr + 256 + d4) = hi;

  float4 k = *(const float4*)(row + 1024 + d4);
  hi[0] = f2b(k.x); lo[0] = f2b(k.x - b2f(hi[0]));
  hi[1] = f2b(k.y); lo[1] = f2b(k.y - b2f(hi[1]));
  hi[2] = f2b(k.z); lo[2] = f2b(k.z - b2f(hi[2]));
  hi[3] = f2b(k.w); lo[3] = f2b(k.w - b2f(hi[3]));
  unsigned short* kr = km + ((size_t)z * 1024 + i) * 384;
  *(ushortx4*)(kr + d4) = hi;
  *(ushortx4*)(kr + 128 + d4) = hi;
  *(ushortx4*)(kr + 256 + d4) = lo;
}

// ---------------------------------------------------------------------------
// per-row fused: p_m = softmax(s_m row) ; dots = p_m*p_v*SCALE + g_l ;
// attn = softmax(dots) -> bf16 in place over pvb.  block = 1 row, 256 thr
// ---------------------------------------------------------------------------
__global__ __launch_bounds__(256) void softmax_combine(
    const float* __restrict__ smb, unsigned short* __restrict__ pvb,
    const float* __restrict__ g_l, int pstart) {
  int i = blockIdx.x, z = blockIdx.y;
  int p = pstart + z;
  const float* srow = smb + ((size_t)z * 1024 + i) * 1024;
  unsigned short* vrow = pvb + ((size_t)z * 1024 + i) * 1024;
  const float* grow = g_l + ((size_t)p * 1024 + i) * 1024;
  int t = threadIdx.x;
  __shared__ float red[4];

  float4 s = *(const float4*)(srow + t * 4);
  float mx = fmaxf(fmaxf(s.x, s.y), fmaxf(s.z, s.w));
#pragma unroll
  for (int o = 32; o; o >>= 1) mx = fmaxf(mx, __shfl_xor(mx, o));
  if ((t & 63) == 0) red[t >> 6] = mx;
  __syncthreads();
  mx = fmaxf(fmaxf(red[0], red[1]), fmaxf(red[2], red[3]));
  __syncthreads();
  float4 e;
  e.x = __expf(s.x - mx); e.y = __expf(s.y - mx);
  e.z = __expf(s.z - mx); e.w = __expf(s.w - mx);
  float sum = e.x + e.y + e.z + e.w;
#pragma unroll
  for (int o = 32; o; o >>= 1) sum += __shfl_xor(sum, o);
  if ((t & 63) == 0) red[t >> 6] = sum;
  __syncthreads();
  float inv = 1.0f / (red[0] + red[1] + red[2] + red[3]);
  __syncthreads();

  ushortx4 pv = *(const ushortx4*)(vrow + t * 4);
  float4 g = *(const float4*)(grow + t * 4);
  float4 d;
  d.x = e.x * inv * b2f(pv[0]) * SCALE_F + g.x;
  d.y = e.y * inv * b2f(pv[1]) * SCALE_F + g.y;
  d.z = e.z * inv * b2f(pv[2]) * SCALE_F + g.z;
  d.w = e.w * inv * b2f(pv[3]) * SCALE_F + g.w;

  float mx2 = fmaxf(fmaxf(d.x, d.y), fmaxf(d.z, d.w));
#pragma unroll
  for (int o = 32; o; o >>= 1) mx2 = fmaxf(mx2, __shfl_xor(mx2, o));
  if ((t & 63) == 0) red[t >> 6] = mx2;
  __syncthreads();
  mx2 = fmaxf(fmaxf(red[0], red[1]), fmaxf(red[2], red[3]));
  __syncthreads();
  float4 e2;
  e2.x = __expf(d.x - mx2); e2.y = __expf(d.y - mx2);
  e2.z = __expf(d.z - mx2); e2.w = __expf(d.w - mx2);
  float sum2 = e2.x + e2.y + e2.z + e2.w;
#pragma unroll
  for (int o = 32; o; o >>= 1) sum2 += __shfl_xor(sum2, o);
  if ((t & 63) == 0) red[t >> 6] = sum2;
  __syncthreads();
  float inv2 = 1.0f / (red[0] + red[1] + red[2] + red[3]);

  ushortx4 o4;
  o4[0] = f2b(e2.x * inv2); o4[1] = f2b(e2.y * inv2);
  o4[2] = f2b(e2.z * inv2); o4[3] = f2b(e2.w * inv2);
  *(ushortx4*)(vrow + t * 4) = o4;
}

// ---------------------------------------------------------------------------
// launch
// ---------------------------------------------------------------------------
extern "C" void kernel_launch(void* const* d_in, const int* in_sizes, int n_in,
                              void* d_out, int out_size, void* d_ws, size_t ws_size,
                              hipStream_t stream) {
  (void)in_sizes; (void)n_in; (void)out_size; (void)ws_size;
  const float* s_v   = (const float*)d_in[0];
  const float* s_m   = (const float*)d_in[1];
  const float* g_l   = (const float*)d_in[2];
  const float* W_qkv = (const float*)d_in[3];
  const float* W_qk  = (const float*)d_in[4];
  const float* W_out = (const float*)d_in[5];
  const float* b_out = (const float*)d_in[6];
  float* out = (float*)d_out;
  char* ws = (char*)d_ws;

  // workspace (283,115,520 B total; phase-aliased regions marked A:/B:)
  unsigned short* sv_bf  = (unsigned short*)(ws);              // A: s_v bf16 16M
  unsigned short* qm384  = (unsigned short*)(ws);              // B: alias, 12.6M
  unsigned short* wtqkv  = (unsigned short*)(ws + 16777216);   // A: 6.3M
  unsigned short* km384  = (unsigned short*)(ws + 16777216);   // B: alias, 12.6M
  unsigned short* wtout  = (unsigned short*)(ws + 29360128);   // persistent 2M
  unsigned short* qkvb   = (unsigned short*)(ws + 31457280);   // persistent 48M
  float*          qkf    = (float*)(ws + 81788928);            // persistent 64M
  unsigned short* vt     = (unsigned short*)(ws + 148897792);  // persistent 16M
  unsigned short* ao     = (unsigned short*)(ws + 165675008);  // persistent 16M
  unsigned short* smhl   = (unsigned short*)(ws + 182452224);  // A: 32M
  float*          smb    = (float*)(ws + 182452224);           // B: alias, 64M
  unsigned short* wqk_hl = (unsigned short*)(ws + 249561088);  // A: 8M
  unsigned short* pvb    = (unsigned short*)(ws + 249561088);  // B: alias, 32M

  // 1. cast s_v -> bf16
  cast_bf16_kernel<<<dim3(8192), 256, 0, stream>>>(s_v, sv_bf, 8388608);
  // 2-3. weight transposes (bf16)
  transpose_any<0><<<dim3(96, 32, 1), 256, 0, stream>>>(
      W_qkv, wtqkv, 1024, 3072, 3072, 1024, 0, 0, 0, 0, 0);
  transpose_any<0><<<dim3(32, 32, 1), 256, 0, stream>>>(
      W_out, wtout, 1024, 1024, 1024, 1024, 0, 0, 0, 0, 0);
  // 4. split s_m -> [hi|lo]  (8192 x 2048)
  split2_kernel<<<dim3(8192), 256, 0, stream>>>(s_m, smhl);
  // 5. transpose+split W_qk -> [2048][2048] = [hi|hi]
  transpose_split_qk<<<dim3(64, 32, 1), 256, 0, stream>>>(W_qk, wqk_hl);
  // 6. qkv = s_v @ W_qkv  (bf16 MFMA 128-tile)
  gemm128<1, 0><<<dim3(24, 64, 1), 256, 0, stream>>>(
      sv_bf, wtqkv, qkvb, nullptr, 1024, 1024, 1024, 3072,
      0, 0, 0, 0, 0, 0, 0, 0, 0, 0);
  // 7. qk = s_m @ W_qk in 2-term split-bf16 (K=2048), fp32 out
  gemm128<0, 0><<<dim3(16, 64, 1), 256, 0, stream>>>(
      smhl, wqk_hl, qkf, nullptr, 2048, 2048, 2048, 2048,
      0, 0, 0, 0, 0, 0, 0, 0, 0, 0);
  // 8. v^T per (b,h): vt[p][d][j]
  transpose_any<2><<<dim3(4, 32, 64), 256, 0, stream>>>(
      qkvb + 2048, vt, 1024, 128, 3072, 1024,
      (long)1024 * 3072, 128, (long)1048576, 131072, 0);

  // 9. chunks of 16 (b,h)-pairs
  for (int c = 0; c < 4; c++) {
    int pstart = c * 16;
    logits_prep<<<dim3(128, 16), 256, 0, stream>>>(qkf, qm384, km384, pstart);
    // s_m logits via 3-term split-bf16 (K=384), fp32 out
    gemm128<0, 0><<<dim3(8, 8, 16), 256, 0, stream>>>(
        qm384, km384, smb, nullptr, 384, 384, 384, 1024,
        (long)1024 * 384, 0, 0, (long)1024 * 384, 0, 0,
        (long)1048576, 0, 0, pstart);
    // p_v = q_v @ k_v^T (bf16, K=128)
    gemm128<1, 0><<<dim3(8, 8, 16), 256, 0, stream>>>(
        qkvb, qkvb + 1024, pvb, nullptr, 128, 3072, 3072, 1024,
        0, (long)1024 * 3072, 128, 0, (long)1024 * 3072, 128,
        (long)1048576, 0, 0, pstart);
    // fused double-softmax + combine -> attn (bf16, in place over pvb)
    softmax_combine<<<dim3(1024, 16), 256, 0, stream>>>(smb, pvb, g_l, pstart);
    // ao = attn @ v (64-row tiles -> 256 blocks), scattered into ao
    gemm64<1, 0><<<dim3(1, 16, 16), 256, 0, stream>>>(
        pvb, vt, ao, nullptr, 1024, 1024, 1024, 1024,
        (long)1048576, 0, 0, 0, (long)1048576, 131072,
        0, (long)1048576, 128, pstart);
  }
  // 10. out = ao @ W_out + b_out (fp32 out)
  gemm128<0, 1><<<dim3(8, 64, 1), 256, 0, stream>>>(
      ao, wtout, out, b_out, 1024, 1024, 1024, 1024,
      0, 0, 0, 0, 0, 0, 0, 0, 0, 0);
}